// Round 10
// baseline (1123.682 us; speedup 1.0000x reference)
//
#include <hip/hip_runtime.h>
#include <math.h>

#define SS 2304
#define C_IN 256
#define HID 512
#define QKV3 1536
#define HEADS 8
#define DH 64
#define BATCH 4
#define EPSV 1e-5f
#define SCALEV 0.125f

typedef short s8v __attribute__((ext_vector_type(8)));
typedef float f4v __attribute__((ext_vector_type(4)));
typedef unsigned int u4v __attribute__((ext_vector_type(4)));
typedef unsigned int uint32;

static __device__ inline unsigned short f2bf(float x) {
    unsigned int u = __float_as_uint(x);
    u += 0x7fffu + ((u >> 16) & 1u);
    return (unsigned short)(u >> 16);
}
static __device__ inline float bf2f(unsigned short h) {
    return __uint_as_float((unsigned int)h << 16);
}
static __device__ inline f4v mm(s8v a, s8v b, f4v c) {
    return __builtin_amdgcn_mfma_f32_16x16x32_bf16(a, b, c, 0, 0, 0);
}
static __device__ inline s8v pk4(uint32 a, uint32 b, uint32 c, uint32 d) {
    u4v t; t[0] = a; t[1] = b; t[2] = c; t[3] = d;
    return __builtin_bit_cast(s8v, t);
}
// hi = round-to-nearest bf16 (bits[15:0]), lo = trunc bf16 of residual (bits[31:16])
static __device__ inline uint32 pk_rnd(float x) {
    unsigned int u = __float_as_uint(x);
    unsigned int uh = (u + (0x7fffu + ((u >> 16) & 1u))) & 0xffff0000u;
    float r = x - __uint_as_float(uh);
    return (uh >> 16) | (__float_as_uint(r) & 0xffff0000u);
}
// trunc/trunc variant (cheap, hot attention path; softmax cancels the bias)
static __device__ inline uint32 pk_trunc(float x) {
    unsigned int u = __float_as_uint(x);
    unsigned int h = u & 0xffff0000u;
    float r = x - __uint_as_float(h);
    return (h >> 16) | (__float_as_uint(r) & 0xffff0000u);
}
// unpack {hi|lo} u32 back to ~fp32
static __device__ inline float unpk(uint32 u) {
    return __uint_as_float(u << 16) + __uint_as_float(u & 0xffff0000u);
}
static __device__ inline uint32 rot16(uint32 u) { return (u >> 16) | (u << 16); }
static __device__ inline u4v rot16v(u4v u) {
    u4v r; r[0] = rot16(u[0]); r[1] = rot16(u[1]); r[2] = rot16(u[2]); r[3] = rot16(u[3]);
    return r;
}

// ---------------- prep: wgint[o][c] = pack(w*g), wsum[o] = sum_c w*g ----------------
__global__ void prep_wgint(const float* __restrict__ w, const float* __restrict__ g,
                           uint32* __restrict__ wgint, float* __restrict__ wsum) {
    __shared__ float red[256];
    int o = blockIdx.x, c = threadIdx.x;
    float v = w[o * C_IN + c] * g[c];
    wgint[o * C_IN + c] = pk_rnd(v);
    red[c] = v;
    __syncthreads();
    for (int st = 128; st > 0; st >>= 1) {
        if (c < st) red[c] += red[c + st];
        __syncthreads();
    }
    if (c == 0) wsum[o] = red[0];
}

// ---------------- prep: pack w_out ----------------
__global__ void prep_woutint(const float* __restrict__ w, uint32* __restrict__ wi) {
    int idx = blockIdx.x * 256 + threadIdx.x;  // 131072 total
    wi[idx] = pk_rnd(w[idx]);
}

// ---------------- prep: RoPE tables in double precision ----------------
__global__ void prep_rope(float* __restrict__ cosT, float* __restrict__ sinT) {
    int idx = blockIdx.x * 256 + threadIdx.x;
    if (idx >= SS * 32) return;
    int s = idx >> 5, f = idx & 31;
    double inv = pow(10000.0, -(double)f / 32.0);
    double ang = (double)s * inv;
    cosT[idx] = (float)cos(ang);
    sinT[idx] = (float)sin(ang);
}

// ------ transpose + pack x -> xTint[b][s][c] u32, and per-c-chunk LN partials ------
__global__ __launch_bounds__(256) void xt_pack(const float* __restrict__ x,
                                               uint32* __restrict__ xTint,
                                               float* __restrict__ psum,
                                               float* __restrict__ psq) {
    __shared__ float tile[64][65];
    __shared__ float sred[4][64];
    __shared__ float qred[4][64];
    int b = blockIdx.z;
    int c0 = blockIdx.y * 64;
    int s0 = blockIdx.x * 64;
    int t = threadIdx.x;
    int sl = t & 63, cg = t >> 6;
    float ps = 0.f, pq = 0.f;
#pragma unroll
    for (int i = 0; i < 16; ++i) {
        int c = cg * 16 + i;
        float v = x[((size_t)b * C_IN + c0 + c) * SS + s0 + sl];
        tile[c][sl] = v;
        ps += v;
        pq += v * v;
    }
    sred[cg][sl] = ps;
    qred[cg][sl] = pq;
    __syncthreads();
    int cl = t & 63, sg = t >> 6;
#pragma unroll
    for (int i = 0; i < 16; ++i) {
        int s = sg * 16 + i;
        xTint[((size_t)b * SS + s0 + s) * C_IN + c0 + cl] = pk_rnd(tile[cl][s]);
    }
    if (t < 64) {
        float S = (sred[0][t] + sred[1][t]) + (sred[2][t] + sred[3][t]);
        float Q = (qred[0][t] + qred[1][t]) + (qred[2][t] + qred[3][t]);
        size_t o = (size_t)blockIdx.y * (BATCH * SS) + (size_t)b * SS + s0 + t;
        psum[o] = S;
        psq[o] = Q;
    }
}

// ---------------- finalize LN stats: mean / rstd per pixel ----------------
__global__ void finalize_stats(const float* __restrict__ psum,
                               const float* __restrict__ psq,
                               float* __restrict__ mean, float* __restrict__ rstd) {
    int p = blockIdx.x * 256 + threadIdx.x;  // 0..9215
    const int NP = BATCH * SS;
    float S = (psum[p] + psum[NP + p]) + (psum[2 * NP + p] + psum[3 * NP + p]);
    float Q = (psq[p] + psq[NP + p]) + (psq[2 * NP + p] + psq[3 * NP + p]);
    float mu = S * (1.0f / C_IN);
    float var = Q * (1.0f / C_IN) - mu * mu;
    mean[p] = mu;
    rstd[p] = rsqrtf(var + EPSV);
}

// ------------- QKV GEMM: interleaved hi/lo bf16 MFMA, LN folded epilogue -------------
// qkvint[b][o][s] = pack(rstd[s]*(sum_c wg[o][c]*x[c][s] - mean[s]*wsum[o]))
__global__ __launch_bounds__(256, 4) void qkv_mfma(
    const uint32* __restrict__ wgint, const uint32* __restrict__ xTint,
    const float* __restrict__ wsum, const float* __restrict__ mean,
    const float* __restrict__ rstd, uint32* __restrict__ qkvint) {
    int b = blockIdx.z;
    int m0 = blockIdx.y * 128;  // o
    int n0 = blockIdx.x * 64;   // s
    int t = threadIdx.x;
    int wv = t >> 6, lane = t & 63, l15 = lane & 15, quad = lane >> 4;
    int wm = wv * 32;
    const uint32* Ab = wgint + (size_t)(m0 + wm) * C_IN;
    const uint32* Bb = xTint + ((size_t)b * SS + n0) * C_IN;
    f4v acc[2][4];
#pragma unroll
    for (int mt = 0; mt < 2; ++mt)
#pragma unroll
        for (int nt = 0; nt < 4; ++nt) acc[mt][nt] = (f4v){0.f, 0.f, 0.f, 0.f};
    u4v af[2][2], bf[2][4];
    auto ldA = [&](int ch, u4v* A) {
#pragma unroll
        for (int mt = 0; mt < 2; ++mt)
            A[mt] = *(const u4v*)(Ab + (size_t)(mt * 16 + l15) * C_IN + ch * 16 + quad * 4);
    };
    auto ldB = [&](int ch, u4v* B) {
#pragma unroll
        for (int nt = 0; nt < 4; ++nt)
            B[nt] = *(const u4v*)(Bb + (size_t)(nt * 16 + l15) * C_IN + ch * 16 + quad * 4);
    };
    ldA(0, af[0]);
    ldB(0, bf[0]);
#pragma unroll 2
    for (int ch = 0; ch < 16; ++ch) {
        int cur = ch & 1, nxt = cur ^ 1;
        if (ch + 1 < 16) { ldA(ch + 1, af[nxt]); ldB(ch + 1, bf[nxt]); }
        u4v br[4];
#pragma unroll
        for (int nt = 0; nt < 4; ++nt) br[nt] = rot16v(bf[cur][nt]);
#pragma unroll
        for (int mt = 0; mt < 2; ++mt) {
            s8v a = __builtin_bit_cast(s8v, af[cur][mt]);
#pragma unroll
            for (int nt = 0; nt < 4; ++nt) {
                acc[mt][nt] = mm(a, __builtin_bit_cast(s8v, bf[cur][nt]), acc[mt][nt]);
                acc[mt][nt] = mm(a, __builtin_bit_cast(s8v, br[nt]), acc[mt][nt]);
            }
        }
    }
    float mnv[4], rsv[4];
#pragma unroll
    for (int nt = 0; nt < 4; ++nt) {
        int n = n0 + nt * 16 + l15;
        mnv[nt] = mean[b * SS + n];
        rsv[nt] = rstd[b * SS + n];
    }
#pragma unroll
    for (int mt = 0; mt < 2; ++mt)
#pragma unroll
        for (int r = 0; r < 4; ++r) {
            int m = m0 + wm + mt * 16 + quad * 4 + r;
            float ws = wsum[m];
            uint32* dst = qkvint + ((size_t)b * QKV3 + m) * SS + n0 + l15;
#pragma unroll
            for (int nt = 0; nt < 4; ++nt)
                dst[nt * 16] = pk_rnd(rsv[nt] * (acc[mt][nt][r] - mnv[nt] * ws));
        }
}

// ------- dwconv 3x3 + RoPE + hi/lo bf16 split.  Input qkvint packed u32.
// Q,K: [bh][s][d] (hi,lo separate); V: [bh][d][s] u32 = hi | lo<<16 -------
__global__ __launch_bounds__(256) void conv_rope(
    const uint32* __restrict__ qkvint, const float* __restrict__ dwq,
    const float* __restrict__ dwk, const float* __restrict__ dwv,
    const float* __restrict__ cosT, const float* __restrict__ sinT,
    unsigned short* __restrict__ qhi, unsigned short* __restrict__ qlo,
    unsigned short* __restrict__ khi, unsigned short* __restrict__ klo,
    uint32* __restrict__ vtint) {
    __shared__ float tile[64][65];
    int b = blockIdx.z;
    int part = blockIdx.y >> 3;
    int h = blockIdx.y & 7;
    int s0 = blockIdx.x * 64;
    int t = threadIdx.x;
    int sl = t & 63, dgrp = t >> 6;
    int s = s0 + sl;
    int y = s / 48, xx = s - y * 48;
    int bh = b * HEADS + h;
    const float* dw = (part == 0) ? dwq : (part == 1) ? dwk : dwv;
#pragma unroll
    for (int i = 0; i < 16; ++i) {
        int d = dgrp * 16 + i;
        int cch = part * HID + h * DH + d;
        const uint32* src = qkvint + ((size_t)b * QKV3 + cch) * SS;
        const float* wp = dw + (h * DH + d) * 9;
        float acc = 0.f;
#pragma unroll
        for (int dy = -1; dy <= 1; ++dy) {
            int yy = y + dy;
            if (yy < 0 || yy >= 48) continue;
#pragma unroll
            for (int dx = -1; dx <= 1; ++dx) {
                int xv = xx + dx;
                if (xv < 0 || xv >= 48) continue;
                acc += wp[(dy + 1) * 3 + (dx + 1)] * unpk(src[yy * 48 + xv]);
            }
        }
        if (part == 2) {
            size_t o = ((size_t)bh * DH + d) * SS + s;
            vtint[o] = pk_rnd(acc);
        } else {
            tile[d][sl] = acc;
        }
    }
    if (part == 2) return;
    __syncthreads();
    int d2 = t & 63, srow = t >> 6;
    unsigned short* hiA = (part == 0) ? qhi : khi;
    unsigned short* loA = (part == 0) ? qlo : klo;
#pragma unroll
    for (int i = 0; i < 16; ++i) {
        int sp = srow + 4 * i;
        float v0 = tile[d2][sp];
        float vp = tile[d2 ^ 32][sp];
        int f = d2 & 31;
        float cv = cosT[(s0 + sp) * 32 + f];
        float sv = sinT[(s0 + sp) * 32 + f];
        float rot = (d2 < 32) ? -vp : vp;
        float val = v0 * cv + rot * sv;
        if (part == 0) val *= SCALEV;
        size_t o = ((size_t)bh * SS + s0 + sp) * DH + d2;
        unsigned short hu = f2bf(val);
        hiA[o] = hu;
        loA[o] = f2bf(val - bf2f(hu));
    }
}

// -------- attention: key-split waves (16-key strip/wave, 64q x 16k), R7 loop order
// (proven spill-free; R9's reorder spilled and was reverted).  NEW: Q fragments live
// in block-shared LDS — all 4 waves read the SAME 64 queries, so the 64 persistent
// qf VGPRs/wave were block-redundant.  Demand drops ~192 -> ~140 unified, so
// launch_bounds (256,3) now sits ABOVE demand (R6/R8 lesson: cap below demand =
// scratch spill) -> 3 waves/SIMD.  Q-area and epilogue area share one LDS union
// (barrier-separated).  S^T = K.Q^T, interleaved hi/lo PV, fixed softmax shift,
// deferred l, phased epilogue. ----
__global__ __launch_bounds__(256, 3) void attn_mfma(
    const unsigned short* __restrict__ qhi, const unsigned short* __restrict__ qlo,
    const unsigned short* __restrict__ khi, const unsigned short* __restrict__ klo,
    const uint32* __restrict__ vtint,
    float* __restrict__ Opart, float* __restrict__ lpart) {
    __shared__ __align__(16) char smem[34816 + 1024];
    // Q area (loop phase): [2][64][72] bf16 = 18432 B (stride 72 avoids conflicts)
    unsigned short (*qs)[64][72] = (unsigned short (*)[64][72])smem;
    // epilogue area (after barrier): [2][64][68] f32 = 34816 B
    float (*ldsO)[64][68] = (float (*)[64][68])smem;
    float (*lsl)[64] = (float (*)[64])(smem + 34816);
    int bh = blockIdx.z;
    int jh = blockIdx.y;
    int i0 = blockIdx.x * 64;
    int t = threadIdx.x;
    int wv = t >> 6;
    int lane = t & 63;
    int l15 = lane & 15;
    int quad = lane >> 4;

    // ---- stage Q (shared by all 4 waves) into LDS: 64 rows x 64 bf16, hi+lo ----
    {
        int row = t >> 3;          // 0..31
        int col = (t & 7) * 8;     // 16B segments
#pragma unroll
        for (int rr = 0; rr < 2; ++rr) {
            int q = row + rr * 32;
            size_t gb = ((size_t)bh * SS + i0 + q) * DH + col;
            *(s8v*)&qs[0][q][col] = *(const s8v*)(qhi + gb);
            *(s8v*)&qs[1][q][col] = *(const s8v*)(qlo + gb);
        }
    }
    __syncthreads();

    f4v oacc[4][4];
#pragma unroll
    for (int dt = 0; dt < 4; ++dt)
#pragma unroll
        for (int ig = 0; ig < 4; ++ig) oacc[dt][ig] = (f4v){0.f, 0.f, 0.f, 0.f};
    float lsum[4] = {0.f, 0.f, 0.f, 0.f};

    const size_t kbh = (size_t)bh * SS * DH;
    const uint32* vbase = vtint + (size_t)bh * DH * SS;
    const int jbase = jh * 1152 + wv * 16;  // wave's strip base; + s*64 per step

    s8v kc[2][4], vc[2][4];
    auto ldK = [&](int s, s8v* K) {
        size_t row = kbh + (size_t)(jbase + s * 64 + l15) * DH + quad * 8;
        K[0] = *(const s8v*)(khi + row);
        K[1] = *(const s8v*)(khi + row + 32);
        K[2] = *(const s8v*)(klo + row);
        K[3] = *(const s8v*)(klo + row + 32);
    };
    auto ldV = [&](int s, s8v* V) {
        size_t col = (size_t)(jbase + s * 64 + quad * 4);
#pragma unroll
        for (int dt = 0; dt < 4; ++dt)
            V[dt] = __builtin_bit_cast(
                s8v, *(const u4v*)(vbase + (size_t)(dt * 16 + l15) * SS + col));
    };
    ldK(0, kc[0]);
    ldV(0, vc[0]);
#pragma unroll 2
    for (int s = 0; s < 18; ++s) {
        int cur = s & 1, nxt = cur ^ 1;
        if (s + 1 < 18) { ldK(s + 1, kc[nxt]); ldV(s + 1, vc[nxt]); }
        // ---- S^T strip = K_strip . Q^T : Q frags read from LDS per use ----
        f4v sv[4];
#pragma unroll
        for (int ig = 0; ig < 4; ++ig) {
            int qrow = ig * 16 + l15;
            s8v qh0 = *(const s8v*)&qs[0][qrow][quad * 8];
            s8v qh1 = *(const s8v*)&qs[0][qrow][32 + quad * 8];
            s8v ql0 = *(const s8v*)&qs[1][qrow][quad * 8];
            s8v ql1 = *(const s8v*)&qs[1][qrow][32 + quad * 8];
            f4v sx = {0.f, 0.f, 0.f, 0.f};
            sx = mm(kc[cur][0], qh0, sx);
            sx = mm(kc[cur][1], qh1, sx);
            sx = mm(kc[cur][0], ql0, sx);
            sx = mm(kc[cur][1], ql1, sx);
            sx = mm(kc[cur][2], qh0, sx);
            sx = mm(kc[cur][3], qh1, sx);
            sv[ig] = sx;
        }
        // ---- p = exp(s); pack B1 = {ph|pl}, B2 = {pl|ph} per key (in-lane!) ----
        s8v B1[4], B2[4];
#pragma unroll
        for (int ig = 0; ig < 4; ++ig) {
            float p0 = __expf(sv[ig][0]), p1 = __expf(sv[ig][1]);
            float p2 = __expf(sv[ig][2]), p3 = __expf(sv[ig][3]);
            lsum[ig] += (p0 + p1) + (p2 + p3);
            uint32 u0 = pk_trunc(p0), u1 = pk_trunc(p1);
            uint32 u2 = pk_trunc(p2), u3 = pk_trunc(p3);
            B1[ig] = pk4(u0, u1, u2, u3);
            B2[ig] = pk4(rot16(u0), rot16(u1), rot16(u2), rot16(u3));
        }
        // ---- O^T += V^T_strip . P^T: A = interleaved {vh|vl} u32/key (1 load) ----
#pragma unroll
        for (int dt = 0; dt < 4; ++dt)
#pragma unroll
            for (int ig = 0; ig < 4; ++ig) {
                oacc[dt][ig] = mm(vc[cur][dt], B1[ig], oacc[dt][ig]);
                oacc[dt][ig] = mm(vc[cur][dt], B2[ig], oacc[dt][ig]);
            }
    }
    // ---- l: reduce over quads (keys) in-wave ----
    float lred[4];
#pragma unroll
    for (int ig = 0; ig < 4; ++ig) {
        float v = lsum[ig];
        v += __shfl_xor(v, 16);
        v += __shfl_xor(v, 32);
        lred[ig] = v;
    }
    // all waves done reading Q-LDS before epilogue reuses the space
    __syncthreads();
#pragma unroll
    for (int ig = 0; ig < 4; ++ig)
        if (quad == 0) lsl[wv][ig * 16 + l15] = lred[ig];
    // ---- phased epilogue: waves 0,1 write slots; waves 2,3 accumulate in-place ----
    if (wv < 2) {
#pragma unroll
        for (int dt = 0; dt < 4; ++dt)
#pragma unroll
            for (int ig = 0; ig < 4; ++ig)
#pragma unroll
                for (int r = 0; r < 4; ++r)
                    ldsO[wv][dt * 16 + quad * 4 + r][ig * 16 + l15] = oacc[dt][ig][r];
    }
    __syncthreads();
    if (wv >= 2) {
#pragma unroll
        for (int dt = 0; dt < 4; ++dt)
#pragma unroll
            for (int ig = 0; ig < 4; ++ig)
#pragma unroll
                for (int r = 0; r < 4; ++r)
                    ldsO[wv - 2][dt * 16 + quad * 4 + r][ig * 16 + l15] += oacc[dt][ig][r];
    }
    __syncthreads();
    // ---- combine 2 slots, write unnormalized partial O^T [jh][bh][d][s] ----
    int d = t >> 2, qg = (t & 3) * 16;
    size_t ob = (((size_t)jh * 32 + bh) * DH + d) * SS + i0 + qg;
#pragma unroll
    for (int j4 = 0; j4 < 4; ++j4) {
        float4 a0 = *(const float4*)&ldsO[0][d][qg + j4 * 4];
        float4 a1 = *(const float4*)&ldsO[1][d][qg + j4 * 4];
        float4 rr;
        rr.x = a0.x + a1.x;
        rr.y = a0.y + a1.y;
        rr.z = a0.z + a1.z;
        rr.w = a0.w + a1.w;
        *(float4*)(Opart + ob + j4 * 4) = rr;
    }
    if (t < 64) {
        float v = (lsl[0][t] + lsl[1][t]) + (lsl[2][t] + lsl[3][t]);
        lpart[((size_t)jh * 32 + bh) * SS + i0 + t] = v;
    }
}

// ------ combine j-halves + normalize + transpose + pack: OTint[b][s][h*64+d] u32 ------
__global__ __launch_bounds__(256) void combine_t(
    const float* __restrict__ Opart, const float* __restrict__ lpart,
    uint32* __restrict__ OTint) {
    __shared__ uint32 tile[64][65];
    int bh = blockIdx.y;
    int s0 = blockIdx.x * 64;
    int b = bh >> 3, h = bh & 7;
    int t = threadIdx.x;
    int sl = t & 63, dg = t >> 6;
    float linv = 1.f / (lpart[(size_t)bh * SS + s0 + sl] +
                        lpart[(size_t)(32 + bh) * SS + s0 + sl]);
#pragma unroll
    for (int i = 0; i < 16; ++i) {
        int d = dg * 16 + i;
        size_t off = ((size_t)bh * DH + d) * SS + s0 + sl;
        float v = (Opart[off] + Opart[off + (size_t)32 * DH * SS]) * linv;
        tile[d][sl] = pk_rnd(v);
    }
    __syncthreads();
    int dl = t & 63, sg = t >> 6;
#pragma unroll
    for (int i = 0; i < 16; ++i) {
        int s = sg * 16 + i;
        OTint[((size_t)b * SS + s0 + s) * HID + h * DH + dl] = tile[dl][s];
    }
}

// ------------- output projection: interleaved hi/lo bf16 MFMA + bias -------------
__global__ __launch_bounds__(256, 4) void outproj_mfma(
    const uint32* __restrict__ OTint, const uint32* __restrict__ woutint,
    const float* __restrict__ b_out, float* __restrict__ out) {
    int b = blockIdx.z;
    int m0 = blockIdx.y * 32;   // o
    int n0 = blockIdx.x * 128;  // s
    int t = threadIdx.x;
    int wv = t >> 6, lane = t & 63, l15 = lane & 15, quad = lane >> 4;
    int wn = wv * 32;
    const uint32* Ab = woutint + (size_t)m0 * HID;
    const uint32* Bb = OTint + ((size_t)b * SS + n0 + wn) * HID;
    f4v acc[2][2];
#pragma unroll
    for (int mt = 0; mt < 2; ++mt)
#pragma unroll
        for (int nt = 0; nt < 2; ++nt) acc[mt][nt] = (f4v){0.f, 0.f, 0.f, 0.f};
    u4v af[2][2], bf[2][2];
    auto ldA = [&](int ch, u4v* A) {
#pragma unroll
        for (int mt = 0; mt < 2; ++mt)
            A[mt] = *(const u4v*)(Ab + (size_t)(mt * 16 + l15) * HID + ch * 16 + quad * 4);
    };
    auto ldB = [&](int ch, u4v* B) {
#pragma unroll
        for (int nt = 0; nt < 2; ++nt)
            B[nt] = *(const u4v*)(Bb + (size_t)(nt * 16 + l15) * HID + ch * 16 + quad * 4);
    };
    ldA(0, af[0]);
    ldB(0, bf[0]);
#pragma unroll 2
    for (int ch = 0; ch < 32; ++ch) {
        int cur = ch & 1, nxt = cur ^ 1;
        if (ch + 1 < 32) { ldA(ch + 1, af[nxt]); ldB(ch + 1, bf[nxt]); }
        u4v br[2];
#pragma unroll
        for (int nt = 0; nt < 2; ++nt) br[nt] = rot16v(bf[cur][nt]);
#pragma unroll
        for (int mt = 0; mt < 2; ++mt) {
            s8v a = __builtin_bit_cast(s8v, af[cur][mt]);
#pragma unroll
            for (int nt = 0; nt < 2; ++nt) {
                acc[mt][nt] = mm(a, __builtin_bit_cast(s8v, bf[cur][nt]), acc[mt][nt]);
                acc[mt][nt] = mm(a, __builtin_bit_cast(s8v, br[nt]), acc[mt][nt]);
            }
        }
    }
#pragma unroll
    for (int mt = 0; mt < 2; ++mt)
#pragma unroll
        for (int r = 0; r < 4; ++r) {
            int o = m0 + mt * 16 + quad * 4 + r;
            float bo = b_out[o];
            float* dst = out + ((size_t)b * C_IN + o) * SS + n0 + wn + l15;
#pragma unroll
            for (int nt = 0; nt < 2; ++nt) dst[nt * 16] = acc[mt][nt][r] + bo;
        }
}

extern "C" void kernel_launch(void* const* d_in, const int* in_sizes, int n_in,
                              void* d_out, int out_size, void* d_ws, size_t ws_size,
                              hipStream_t stream) {
    (void)in_sizes; (void)n_in; (void)out_size; (void)ws_size;
    const float* x     = (const float*)d_in[0];
    const float* g     = (const float*)d_in[1];
    const float* w_qkv = (const float*)d_in[2];
    const float* dwq   = (const float*)d_in[3];
    const float* dwk   = (const float*)d_in[4];
    const float* dwv   = (const float*)d_in[5];
    const float* w_out = (const float*)d_in[6];
    const float* b_out = (const float*)d_in[7];
    float* out = (float*)d_out;

    char* ws = (char*)d_ws;
    size_t off = 0;
    auto alloc = [&](size_t nbytes) -> void* {
        char* p = ws + off;
        off = (off + nbytes + 255) & ~(size_t)255;
        return (void*)p;
    };
    const size_t NSD = (size_t)BATCH * HEADS * SS * DH;  // 4.7M elements
    uint32* wgint   = (uint32*)alloc((size_t)QKV3 * C_IN * 4);
    uint32* woutint = (uint32*)alloc((size_t)C_IN * HID * 4);
    float* wsum = (float*)alloc((size_t)QKV3 * 4);
    float* mean = (float*)alloc((size_t)BATCH * SS * 4);
    float* rstd = (float*)alloc((size_t)BATCH * SS * 4);
    float* psum = (float*)alloc((size_t)4 * BATCH * SS * 4);
    float* psq  = (float*)alloc((size_t)4 * BATCH * SS * 4);
    float* cosT = (float*)alloc((size_t)SS * 32 * 4);
    float* sinT = (float*)alloc((size_t)SS * 32 * 4);
    // scratchA sized for the larger of {qkvint u32 (28.3 MB)} and
    // {Opart 2*NSD f32 + OTint NSD u32 (56.6 MB)} — time-disjoint uses
    char* scratchA = (char*)alloc((size_t)3 * NSD * 4);
    unsigned short* qhi  = (unsigned short*)alloc(NSD * 2);
    unsigned short* qlo  = (unsigned short*)alloc(NSD * 2);
    unsigned short* khi  = (unsigned short*)alloc(NSD * 2);
    unsigned short* klo  = (unsigned short*)alloc(NSD * 2);
    uint32* vtint = (uint32*)alloc(NSD * 4);
    float* lpart = (float*)alloc((size_t)2 * 32 * SS * 4);
    // aliases (time-disjoint):
    uint32* xTint  = (uint32*)qhi;      // dead before conv_rope writes qhi
    uint32* qkvint = (uint32*)scratchA; // dead after conv_rope
    float*  Opart  = (float*)scratchA;
    uint32* OTint  = (uint32*)(scratchA + (size_t)2 * NSD * 4);

    prep_wgint<<<QKV3, 256, 0, stream>>>(w_qkv, g, wgint, wsum);
    prep_woutint<<<512, 256, 0, stream>>>(w_out, woutint);
    prep_rope<<<288, 256, 0, stream>>>(cosT, sinT);
    xt_pack<<<dim3(36, 4, BATCH), 256, 0, stream>>>(x, xTint, psum, psq);
    finalize_stats<<<36, 256, 0, stream>>>(psum, psq, mean, rstd);
    qkv_mfma<<<dim3(36, 12, BATCH), 256, 0, stream>>>(wgint, xTint, wsum, mean, rstd,
                                                      qkvint);
    conv_rope<<<dim3(36, 24, BATCH), 256, 0, stream>>>(qkvint, dwq, dwk, dwv, cosT, sinT,
                                                       qhi, qlo, khi, klo, vtint);
    attn_mfma<<<dim3(36, 2, 32), 256, 0, stream>>>(qhi, qlo, khi, klo, vtint,
                                                   Opart, lpart);
    combine_t<<<dim3(36, 32), 256, 0, stream>>>(Opart, lpart, OTint);
    outproj_mfma<<<dim3(18, 8, BATCH), 256, 0, stream>>>(OTint, woutint, b_out, out);
}

// Round 12
// 477.185 us; speedup vs baseline: 2.3548x; 2.3548x over previous
//
#include <hip/hip_runtime.h>
#include <math.h>

#define SS 2304
#define C_IN 256
#define HID 512
#define QKV3 1536
#define HEADS 8
#define DH 64
#define BATCH 4
#define EPSV 1e-5f
#define SCALEV 0.125f

typedef short s8v __attribute__((ext_vector_type(8)));
typedef float f4v __attribute__((ext_vector_type(4)));
typedef unsigned int u4v __attribute__((ext_vector_type(4)));
typedef unsigned int uint32;

static __device__ inline unsigned short f2bf(float x) {
    unsigned int u = __float_as_uint(x);
    u += 0x7fffu + ((u >> 16) & 1u);
    return (unsigned short)(u >> 16);
}
static __device__ inline float bf2f(unsigned short h) {
    return __uint_as_float((unsigned int)h << 16);
}
static __device__ inline f4v mm(s8v a, s8v b, f4v c) {
    return __builtin_amdgcn_mfma_f32_16x16x32_bf16(a, b, c, 0, 0, 0);
}
static __device__ inline s8v pk4(uint32 a, uint32 b, uint32 c, uint32 d) {
    u4v t; t[0] = a; t[1] = b; t[2] = c; t[3] = d;
    return __builtin_bit_cast(s8v, t);
}
// hi = round-to-nearest bf16 (bits[15:0]), lo = trunc bf16 of residual (bits[31:16])
static __device__ inline uint32 pk_rnd(float x) {
    unsigned int u = __float_as_uint(x);
    unsigned int uh = (u + (0x7fffu + ((u >> 16) & 1u))) & 0xffff0000u;
    float r = x - __uint_as_float(uh);
    return (uh >> 16) | (__float_as_uint(r) & 0xffff0000u);
}
// trunc/trunc variant (cheap, hot attention path; softmax cancels the bias)
static __device__ inline uint32 pk_trunc(float x) {
    unsigned int u = __float_as_uint(x);
    unsigned int h = u & 0xffff0000u;
    float r = x - __uint_as_float(h);
    return (h >> 16) | (__float_as_uint(r) & 0xffff0000u);
}
// unpack {hi|lo} u32 back to ~fp32
static __device__ inline float unpk(uint32 u) {
    return __uint_as_float(u << 16) + __uint_as_float(u & 0xffff0000u);
}
static __device__ inline uint32 rot16(uint32 u) { return (u >> 16) | (u << 16); }
static __device__ inline u4v rot16v(u4v u) {
    u4v r; r[0] = rot16(u[0]); r[1] = rot16(u[1]); r[2] = rot16(u[2]); r[3] = rot16(u[3]);
    return r;
}

// ---- merged prep: [0,1536) wgint+wsum | [1536,2048) woutint | [2048,2336) rope ----
__global__ void prep_all(const float* __restrict__ w_qkv, const float* __restrict__ g,
                         uint32* __restrict__ wgint, float* __restrict__ wsum,
                         const float* __restrict__ w_out, uint32* __restrict__ woutint,
                         float* __restrict__ cosT, float* __restrict__ sinT) {
    __shared__ float red[256];
    int bid = blockIdx.x;
    int t = threadIdx.x;
    if (bid < QKV3) {
        int o = bid, c = t;
        float v = w_qkv[o * C_IN + c] * g[c];
        wgint[o * C_IN + c] = pk_rnd(v);
        red[c] = v;
        __syncthreads();
        for (int st = 128; st > 0; st >>= 1) {
            if (c < st) red[c] += red[c + st];
            __syncthreads();
        }
        if (c == 0) wsum[o] = red[0];
    } else if (bid < QKV3 + 512) {
        int idx = (bid - QKV3) * 256 + t;  // 131072 total
        woutint[idx] = pk_rnd(w_out[idx]);
    } else {
        int idx = (bid - QKV3 - 512) * 256 + t;  // 73728 total
        int s = idx >> 5, f = idx & 31;
        double inv = pow(10000.0, -(double)f / 32.0);
        double ang = (double)s * inv;
        cosT[idx] = (float)cos(ang);
        sinT[idx] = (float)sin(ang);
    }
}

// ------ transpose + pack x -> xTint[b][s][c] u32, and per-c-chunk LN partials ------
__global__ __launch_bounds__(256) void xt_pack(const float* __restrict__ x,
                                               uint32* __restrict__ xTint,
                                               float* __restrict__ psum,
                                               float* __restrict__ psq) {
    __shared__ float tile[64][65];
    __shared__ float sred[4][64];
    __shared__ float qred[4][64];
    int b = blockIdx.z;
    int c0 = blockIdx.y * 64;
    int s0 = blockIdx.x * 64;
    int t = threadIdx.x;
    int sl = t & 63, cg = t >> 6;
    float ps = 0.f, pq = 0.f;
#pragma unroll
    for (int i = 0; i < 16; ++i) {
        int c = cg * 16 + i;
        float v = x[((size_t)b * C_IN + c0 + c) * SS + s0 + sl];
        tile[c][sl] = v;
        ps += v;
        pq += v * v;
    }
    sred[cg][sl] = ps;
    qred[cg][sl] = pq;
    __syncthreads();
    int cl = t & 63, sg = t >> 6;
#pragma unroll
    for (int i = 0; i < 16; ++i) {
        int s = sg * 16 + i;
        xTint[((size_t)b * SS + s0 + s) * C_IN + c0 + cl] = pk_rnd(tile[cl][s]);
    }
    if (t < 64) {
        float S = (sred[0][t] + sred[1][t]) + (sred[2][t] + sred[3][t]);
        float Q = (qred[0][t] + qred[1][t]) + (qred[2][t] + qred[3][t]);
        size_t o = (size_t)blockIdx.y * (BATCH * SS) + (size_t)b * SS + s0 + t;
        psum[o] = S;
        psq[o] = Q;
    }
}

// ---------------- finalize LN stats: mean / rstd per pixel ----------------
__global__ void finalize_stats(const float* __restrict__ psum,
                               const float* __restrict__ psq,
                               float* __restrict__ mean, float* __restrict__ rstd) {
    int p = blockIdx.x * 256 + threadIdx.x;  // 0..9215
    const int NP = BATCH * SS;
    float S = (psum[p] + psum[NP + p]) + (psum[2 * NP + p] + psum[3 * NP + p]);
    float Q = (psq[p] + psq[NP + p]) + (psq[2 * NP + p] + psq[3 * NP + p]);
    float mu = S * (1.0f / C_IN);
    float var = Q * (1.0f / C_IN) - mu * mu;
    mean[p] = mu;
    rstd[p] = rsqrtf(var + EPSV);
}

// ------------- QKV GEMM: interleaved hi/lo bf16 MFMA, LN folded epilogue -------------
// qkvint[b][o][s] = pack(rstd[s]*(sum_c wg[o][c]*x[c][s] - mean[s]*wsum[o]))
__global__ __launch_bounds__(256, 4) void qkv_mfma(
    const uint32* __restrict__ wgint, const uint32* __restrict__ xTint,
    const float* __restrict__ wsum, const float* __restrict__ mean,
    const float* __restrict__ rstd, uint32* __restrict__ qkvint) {
    int b = blockIdx.z;
    int m0 = blockIdx.y * 128;  // o
    int n0 = blockIdx.x * 64;   // s
    int t = threadIdx.x;
    int wv = t >> 6, lane = t & 63, l15 = lane & 15, quad = lane >> 4;
    int wm = wv * 32;
    const uint32* Ab = wgint + (size_t)(m0 + wm) * C_IN;
    const uint32* Bb = xTint + ((size_t)b * SS + n0) * C_IN;
    f4v acc[2][4];
#pragma unroll
    for (int mt = 0; mt < 2; ++mt)
#pragma unroll
        for (int nt = 0; nt < 4; ++nt) acc[mt][nt] = (f4v){0.f, 0.f, 0.f, 0.f};
    u4v af[2][2], bf[2][4];
    auto ldA = [&](int ch, u4v* A) {
#pragma unroll
        for (int mt = 0; mt < 2; ++mt)
            A[mt] = *(const u4v*)(Ab + (size_t)(mt * 16 + l15) * C_IN + ch * 16 + quad * 4);
    };
    auto ldB = [&](int ch, u4v* B) {
#pragma unroll
        for (int nt = 0; nt < 4; ++nt)
            B[nt] = *(const u4v*)(Bb + (size_t)(nt * 16 + l15) * C_IN + ch * 16 + quad * 4);
    };
    ldA(0, af[0]);
    ldB(0, bf[0]);
#pragma unroll 2
    for (int ch = 0; ch < 16; ++ch) {
        int cur = ch & 1, nxt = cur ^ 1;
        if (ch + 1 < 16) { ldA(ch + 1, af[nxt]); ldB(ch + 1, bf[nxt]); }
        u4v br[4];
#pragma unroll
        for (int nt = 0; nt < 4; ++nt) br[nt] = rot16v(bf[cur][nt]);
#pragma unroll
        for (int mt = 0; mt < 2; ++mt) {
            s8v a = __builtin_bit_cast(s8v, af[cur][mt]);
#pragma unroll
            for (int nt = 0; nt < 4; ++nt) {
                acc[mt][nt] = mm(a, __builtin_bit_cast(s8v, bf[cur][nt]), acc[mt][nt]);
                acc[mt][nt] = mm(a, __builtin_bit_cast(s8v, br[nt]), acc[mt][nt]);
            }
        }
    }
    float mnv[4], rsv[4];
#pragma unroll
    for (int nt = 0; nt < 4; ++nt) {
        int n = n0 + nt * 16 + l15;
        mnv[nt] = mean[b * SS + n];
        rsv[nt] = rstd[b * SS + n];
    }
#pragma unroll
    for (int mt = 0; mt < 2; ++mt)
#pragma unroll
        for (int r = 0; r < 4; ++r) {
            int m = m0 + wm + mt * 16 + quad * 4 + r;
            float ws = wsum[m];
            uint32* dst = qkvint + ((size_t)b * QKV3 + m) * SS + n0 + l15;
#pragma unroll
            for (int nt = 0; nt < 4; ++nt)
                dst[nt * 16] = pk_rnd(rsv[nt] * (acc[mt][nt][r] - mnv[nt] * ws));
        }
}

// ------- dwconv 3x3 + RoPE + hi/lo bf16 split.  Input qkvint packed u32.
// Q,K: [bh][s][d] (hi,lo separate); V: [bh][d][s] u32 = hi | lo<<16 -------
__global__ __launch_bounds__(256) void conv_rope(
    const uint32* __restrict__ qkvint, const float* __restrict__ dwq,
    const float* __restrict__ dwk, const float* __restrict__ dwv,
    const float* __restrict__ cosT, const float* __restrict__ sinT,
    unsigned short* __restrict__ qhi, unsigned short* __restrict__ qlo,
    unsigned short* __restrict__ khi, unsigned short* __restrict__ klo,
    uint32* __restrict__ vtint) {
    __shared__ float tile[64][65];
    int b = blockIdx.z;
    int part = blockIdx.y >> 3;
    int h = blockIdx.y & 7;
    int s0 = blockIdx.x * 64;
    int t = threadIdx.x;
    int sl = t & 63, dgrp = t >> 6;
    int s = s0 + sl;
    int y = s / 48, xx = s - y * 48;
    int bh = b * HEADS + h;
    const float* dw = (part == 0) ? dwq : (part == 1) ? dwk : dwv;
#pragma unroll
    for (int i = 0; i < 16; ++i) {
        int d = dgrp * 16 + i;
        int cch = part * HID + h * DH + d;
        const uint32* src = qkvint + ((size_t)b * QKV3 + cch) * SS;
        const float* wp = dw + (h * DH + d) * 9;
        float acc = 0.f;
#pragma unroll
        for (int dy = -1; dy <= 1; ++dy) {
            int yy = y + dy;
            if (yy < 0 || yy >= 48) continue;
#pragma unroll
            for (int dx = -1; dx <= 1; ++dx) {
                int xv = xx + dx;
                if (xv < 0 || xv >= 48) continue;
                acc += wp[(dy + 1) * 3 + (dx + 1)] * unpk(src[yy * 48 + xv]);
            }
        }
        if (part == 2) {
            size_t o = ((size_t)bh * DH + d) * SS + s;
            vtint[o] = pk_rnd(acc);
        } else {
            tile[d][sl] = acc;
        }
    }
    if (part == 2) return;
    __syncthreads();
    int d2 = t & 63, srow = t >> 6;
    unsigned short* hiA = (part == 0) ? qhi : khi;
    unsigned short* loA = (part == 0) ? qlo : klo;
#pragma unroll
    for (int i = 0; i < 16; ++i) {
        int sp = srow + 4 * i;
        float v0 = tile[d2][sp];
        float vp = tile[d2 ^ 32][sp];
        int f = d2 & 31;
        float cv = cosT[(s0 + sp) * 32 + f];
        float sv = sinT[(s0 + sp) * 32 + f];
        float rot = (d2 < 32) ? -vp : vp;
        float val = v0 * cv + rot * sv;
        if (part == 0) val *= SCALEV;
        size_t o = ((size_t)bh * SS + s0 + sp) * DH + d2;
        unsigned short hu = f2bf(val);
        hiA[o] = hu;
        loA[o] = f2bf(val - bf2f(hu));
    }
}

// -------- attention: key-split waves (16-key strip/wave, 64q x 16k), EXACT R7 loop
// (only spill-free config found: ~192 unified regs, 2 waves/SIMD, bounds (256,2);
// R6/R8/R9/R10 all spilled trying to exceed it — caps below demand = scratch HBM).
// NO j-split: each block runs all 36 key-steps, so the epilogue owns the full
// softmax l and writes normalized+packed OTint[b][s][h*64+d] directly — kills
// the combine_t kernel and 150 MB of Opart/lpart traffic.  S^T = K.Q^T, interleaved
// hi/lo PV, fixed softmax shift (scores O(1)), deferred l, phased-LDS epilogue. ----
__global__ __launch_bounds__(256, 2) void attn_mfma(
    const unsigned short* __restrict__ qhi, const unsigned short* __restrict__ qlo,
    const unsigned short* __restrict__ khi, const unsigned short* __restrict__ klo,
    const uint32* __restrict__ vtint, uint32* __restrict__ OTint) {
    __shared__ float lds[2][64][68];
    __shared__ float lsl[4][64];
    int bh = blockIdx.y;
    int i0 = blockIdx.x * 64;
    int t = threadIdx.x;
    int wv = t >> 6;
    int lane = t & 63;
    int l15 = lane & 15;
    int quad = lane >> 4;

    // Q B-frags: B[n=query(l15)][k=d(quad*8+j)] for 4 query groups, hi/lo
    s8v qf[4][4];
#pragma unroll
    for (int ig = 0; ig < 4; ++ig) {
        size_t qb = ((size_t)bh * SS + i0 + ig * 16 + l15) * DH + quad * 8;
        qf[ig][0] = *(const s8v*)(qhi + qb);
        qf[ig][1] = *(const s8v*)(qhi + qb + 32);
        qf[ig][2] = *(const s8v*)(qlo + qb);
        qf[ig][3] = *(const s8v*)(qlo + qb + 32);
    }
    f4v oacc[4][4];
#pragma unroll
    for (int dt = 0; dt < 4; ++dt)
#pragma unroll
        for (int ig = 0; ig < 4; ++ig) oacc[dt][ig] = (f4v){0.f, 0.f, 0.f, 0.f};
    float lsum[4] = {0.f, 0.f, 0.f, 0.f};

    const size_t kbh = (size_t)bh * SS * DH;
    const uint32* vbase = vtint + (size_t)bh * DH * SS;
    const int jbase = wv * 16;  // wave's strip base; + s*64 per step

    s8v kc[2][4], vc[2][4];
    auto ldK = [&](int s, s8v* K) {
        size_t row = kbh + (size_t)(jbase + s * 64 + l15) * DH + quad * 8;
        K[0] = *(const s8v*)(khi + row);
        K[1] = *(const s8v*)(khi + row + 32);
        K[2] = *(const s8v*)(klo + row);
        K[3] = *(const s8v*)(klo + row + 32);
    };
    auto ldV = [&](int s, s8v* V) {
        size_t col = (size_t)(jbase + s * 64 + quad * 4);
#pragma unroll
        for (int dt = 0; dt < 4; ++dt)
            V[dt] = __builtin_bit_cast(
                s8v, *(const u4v*)(vbase + (size_t)(dt * 16 + l15) * SS + col));
    };
    ldK(0, kc[0]);
    ldV(0, vc[0]);
#pragma unroll 2
    for (int s = 0; s < 36; ++s) {
        int cur = s & 1, nxt = cur ^ 1;
        if (s + 1 < 36) { ldK(s + 1, kc[nxt]); ldV(s + 1, vc[nxt]); }
        // ---- S^T strip = K_strip . Q^T : C row = key quad*4+r, col = query l15 ----
        f4v sv[4];
#pragma unroll
        for (int ig = 0; ig < 4; ++ig) {
            f4v sx = {0.f, 0.f, 0.f, 0.f};
            sx = mm(kc[cur][0], qf[ig][0], sx);
            sx = mm(kc[cur][1], qf[ig][1], sx);
            sx = mm(kc[cur][0], qf[ig][2], sx);
            sx = mm(kc[cur][1], qf[ig][3], sx);
            sx = mm(kc[cur][2], qf[ig][0], sx);
            sx = mm(kc[cur][3], qf[ig][1], sx);
            sv[ig] = sx;
        }
        // ---- p = exp(s); pack B1 = {ph|pl}, B2 = {pl|ph} per key (in-lane!) ----
        s8v B1[4], B2[4];
#pragma unroll
        for (int ig = 0; ig < 4; ++ig) {
            float p0 = __expf(sv[ig][0]), p1 = __expf(sv[ig][1]);
            float p2 = __expf(sv[ig][2]), p3 = __expf(sv[ig][3]);
            lsum[ig] += (p0 + p1) + (p2 + p3);
            uint32 u0 = pk_trunc(p0), u1 = pk_trunc(p1);
            uint32 u2 = pk_trunc(p2), u3 = pk_trunc(p3);
            B1[ig] = pk4(u0, u1, u2, u3);
            B2[ig] = pk4(rot16(u0), rot16(u1), rot16(u2), rot16(u3));
        }
        // ---- O^T += V^T_strip . P^T: A = interleaved {vh|vl} u32/key (1 load) ----
        // mm(A,B1) = vh.ph + vl.pl ; mm(A,B2) = vh.pl + vl.ph  => exact product
#pragma unroll
        for (int dt = 0; dt < 4; ++dt)
#pragma unroll
            for (int ig = 0; ig < 4; ++ig) {
                oacc[dt][ig] = mm(vc[cur][dt], B1[ig], oacc[dt][ig]);
                oacc[dt][ig] = mm(vc[cur][dt], B2[ig], oacc[dt][ig]);
            }
    }
    // ---- l: reduce over quads (keys) in-wave; cross-wave via LDS ----
#pragma unroll
    for (int ig = 0; ig < 4; ++ig) {
        float v = lsum[ig];
        v += __shfl_xor(v, 16);
        v += __shfl_xor(v, 32);
        if (quad == 0) lsl[wv][ig * 16 + l15] = v;
    }
    // ---- phased epilogue: waves 0,1 write slots; waves 2,3 accumulate in-place ----
    if (wv < 2) {
#pragma unroll
        for (int dt = 0; dt < 4; ++dt)
#pragma unroll
            for (int ig = 0; ig < 4; ++ig)
#pragma unroll
                for (int r = 0; r < 4; ++r)
                    lds[wv][dt * 16 + quad * 4 + r][ig * 16 + l15] = oacc[dt][ig][r];
    }
    __syncthreads();
    if (wv >= 2) {
#pragma unroll
        for (int dt = 0; dt < 4; ++dt)
#pragma unroll
            for (int ig = 0; ig < 4; ++ig)
#pragma unroll
                for (int r = 0; r < 4; ++r)
                    lds[wv - 2][dt * 16 + quad * 4 + r][ig * 16 + l15] += oacc[dt][ig][r];
    }
    __syncthreads();
    // ---- normalize + pack + write OTint[b][s][h*64+d] (full l known: no combine) ----
    int q = t >> 2, dg = t & 3;
    float linv = 1.f / ((lsl[0][q] + lsl[1][q]) + (lsl[2][q] + lsl[3][q]));
    int b = bh >> 3, h = bh & 7;
    uint32* dst = OTint + ((size_t)b * SS + i0 + q) * HID + h * DH + dg * 16;
    u4v ov[4];
#pragma unroll
    for (int j4 = 0; j4 < 4; ++j4)
#pragma unroll
        for (int i = 0; i < 4; ++i) {
            int d = dg * 16 + j4 * 4 + i;
            ov[j4][i] = pk_rnd((lds[0][d][q] + lds[1][d][q]) * linv);
        }
#pragma unroll
    for (int j4 = 0; j4 < 4; ++j4) *(u4v*)(dst + j4 * 4) = ov[j4];
}

// ------------- output projection: interleaved hi/lo bf16 MFMA + bias -------------
__global__ __launch_bounds__(256, 4) void outproj_mfma(
    const uint32* __restrict__ OTint, const uint32* __restrict__ woutint,
    const float* __restrict__ b_out, float* __restrict__ out) {
    int b = blockIdx.z;
    int m0 = blockIdx.y * 32;   // o
    int n0 = blockIdx.x * 128;  // s
    int t = threadIdx.x;
    int wv = t >> 6, lane = t & 63, l15 = lane & 15, quad = lane >> 4;
    int wn = wv * 32;
    const uint32* Ab = woutint + (size_t)m0 * HID;
    const uint32* Bb = OTint + ((size_t)b * SS + n0 + wn) * HID;
    f4v acc[2][2];
#pragma unroll
    for (int mt = 0; mt < 2; ++mt)
#pragma unroll
        for (int nt = 0; nt < 2; ++nt) acc[mt][nt] = (f4v){0.f, 0.f, 0.f, 0.f};
    u4v af[2][2], bf[2][2];
    auto ldA = [&](int ch, u4v* A) {
#pragma unroll
        for (int mt = 0; mt < 2; ++mt)
            A[mt] = *(const u4v*)(Ab + (size_t)(mt * 16 + l15) * HID + ch * 16 + quad * 4);
    };
    auto ldB = [&](int ch, u4v* B) {
#pragma unroll
        for (int nt = 0; nt < 2; ++nt)
            B[nt] = *(const u4v*)(Bb + (size_t)(nt * 16 + l15) * HID + ch * 16 + quad * 4);
    };
    ldA(0, af[0]);
    ldB(0, bf[0]);
#pragma unroll 2
    for (int ch = 0; ch < 32; ++ch) {
        int cur = ch & 1, nxt = cur ^ 1;
        if (ch + 1 < 32) { ldA(ch + 1, af[nxt]); ldB(ch + 1, bf[nxt]); }
        u4v br[2];
#pragma unroll
        for (int nt = 0; nt < 2; ++nt) br[nt] = rot16v(bf[cur][nt]);
#pragma unroll
        for (int mt = 0; mt < 2; ++mt) {
            s8v a = __builtin_bit_cast(s8v, af[cur][mt]);
#pragma unroll
            for (int nt = 0; nt < 2; ++nt) {
                acc[mt][nt] = mm(a, __builtin_bit_cast(s8v, bf[cur][nt]), acc[mt][nt]);
                acc[mt][nt] = mm(a, __builtin_bit_cast(s8v, br[nt]), acc[mt][nt]);
            }
        }
    }
#pragma unroll
    for (int mt = 0; mt < 2; ++mt)
#pragma unroll
        for (int r = 0; r < 4; ++r) {
            int o = m0 + mt * 16 + quad * 4 + r;
            float bo = b_out[o];
            float* dst = out + ((size_t)b * C_IN + o) * SS + n0 + wn + l15;
#pragma unroll
            for (int nt = 0; nt < 2; ++nt) dst[nt * 16] = acc[mt][nt][r] + bo;
        }
}

extern "C" void kernel_launch(void* const* d_in, const int* in_sizes, int n_in,
                              void* d_out, int out_size, void* d_ws, size_t ws_size,
                              hipStream_t stream) {
    (void)in_sizes; (void)n_in; (void)out_size; (void)ws_size;
    const float* x     = (const float*)d_in[0];
    const float* g     = (const float*)d_in[1];
    const float* w_qkv = (const float*)d_in[2];
    const float* dwq   = (const float*)d_in[3];
    const float* dwk   = (const float*)d_in[4];
    const float* dwv   = (const float*)d_in[5];
    const float* w_out = (const float*)d_in[6];
    const float* b_out = (const float*)d_in[7];
    float* out = (float*)d_out;

    char* ws = (char*)d_ws;
    size_t off = 0;
    auto alloc = [&](size_t nbytes) -> void* {
        char* p = ws + off;
        off = (off + nbytes + 255) & ~(size_t)255;
        return (void*)p;
    };
    const size_t NSD = (size_t)BATCH * HEADS * SS * DH;  // 4.7M elements
    uint32* wgint   = (uint32*)alloc((size_t)QKV3 * C_IN * 4);
    uint32* woutint = (uint32*)alloc((size_t)C_IN * HID * 4);
    float* wsum = (float*)alloc((size_t)QKV3 * 4);
    float* mean = (float*)alloc((size_t)BATCH * SS * 4);
    float* rstd = (float*)alloc((size_t)BATCH * SS * 4);
    float* psum = (float*)alloc((size_t)4 * BATCH * SS * 4);
    float* psq  = (float*)alloc((size_t)4 * BATCH * SS * 4);
    float* cosT = (float*)alloc((size_t)SS * 32 * 4);
    float* sinT = (float*)alloc((size_t)SS * 32 * 4);
    // scratchA: qkvint = BATCH*QKV3*SS u32 = 3*NSD u32 = 56.6 MB (R11 bug: was 2*NSD).
    // OTint (NSD u32) aliases its start — qkvint dead after conv_rope.
    char* scratchA = (char*)alloc((size_t)3 * NSD * 4);
    unsigned short* qhi  = (unsigned short*)alloc(NSD * 2);
    unsigned short* qlo  = (unsigned short*)alloc(NSD * 2);
    unsigned short* khi  = (unsigned short*)alloc(NSD * 2);
    unsigned short* klo  = (unsigned short*)alloc(NSD * 2);
    uint32* vtint = (uint32*)alloc(NSD * 4);
    // aliases (time-disjoint):
    uint32* xTint  = (uint32*)qhi;      // dead before conv_rope writes qhi
    uint32* qkvint = (uint32*)scratchA; // dead after conv_rope
    uint32* OTint  = (uint32*)scratchA;

    prep_all<<<QKV3 + 512 + 288, 256, 0, stream>>>(w_qkv, g, wgint, wsum,
                                                   w_out, woutint, cosT, sinT);
    xt_pack<<<dim3(36, 4, BATCH), 256, 0, stream>>>(x, xTint, psum, psq);
    finalize_stats<<<36, 256, 0, stream>>>(psum, psq, mean, rstd);
    qkv_mfma<<<dim3(36, 12, BATCH), 256, 0, stream>>>(wgint, xTint, wsum, mean, rstd,
                                                      qkvint);
    conv_rope<<<dim3(36, 24, BATCH), 256, 0, stream>>>(qkvint, dwq, dwk, dwv, cosT, sinT,
                                                       qhi, qlo, khi, klo, vtint);
    attn_mfma<<<dim3(36, 32), 256, 0, stream>>>(qhi, qlo, khi, klo, vtint, OTint);
    outproj_mfma<<<dim3(18, 8, BATCH), 256, 0, stream>>>(OTint, woutint, b_out, out);
}

// Round 13
// 475.777 us; speedup vs baseline: 2.3618x; 1.0030x over previous
//
#include <hip/hip_runtime.h>
#include <math.h>

#define SS 2304
#define C_IN 256
#define HID 512
#define QKV3 1536
#define HEADS 8
#define DH 64
#define BATCH 4
#define EPSV 1e-5f
#define SCALEV 0.125f

typedef short s8v __attribute__((ext_vector_type(8)));
typedef float f4v __attribute__((ext_vector_type(4)));
typedef unsigned int u4v __attribute__((ext_vector_type(4)));
typedef unsigned int uint32;

static __device__ inline unsigned short f2bf(float x) {
    unsigned int u = __float_as_uint(x);
    u += 0x7fffu + ((u >> 16) & 1u);
    return (unsigned short)(u >> 16);
}
static __device__ inline float bf2f(unsigned short h) {
    return __uint_as_float((unsigned int)h << 16);
}
static __device__ inline f4v mm(s8v a, s8v b, f4v c) {
    return __builtin_amdgcn_mfma_f32_16x16x32_bf16(a, b, c, 0, 0, 0);
}
static __device__ inline s8v pk4(uint32 a, uint32 b, uint32 c, uint32 d) {
    u4v t; t[0] = a; t[1] = b; t[2] = c; t[3] = d;
    return __builtin_bit_cast(s8v, t);
}
// hi = round-to-nearest bf16 (bits[15:0]), lo = trunc bf16 of residual (bits[31:16])
static __device__ inline uint32 pk_rnd(float x) {
    unsigned int u = __float_as_uint(x);
    unsigned int uh = (u + (0x7fffu + ((u >> 16) & 1u))) & 0xffff0000u;
    float r = x - __uint_as_float(uh);
    return (uh >> 16) | (__float_as_uint(r) & 0xffff0000u);
}
// trunc/trunc variant (cheap, hot attention path; softmax cancels the bias)
static __device__ inline uint32 pk_trunc(float x) {
    unsigned int u = __float_as_uint(x);
    unsigned int h = u & 0xffff0000u;
    float r = x - __uint_as_float(h);
    return (h >> 16) | (__float_as_uint(r) & 0xffff0000u);
}
// unpack {hi|lo} u32 back to ~fp32
static __device__ inline float unpk(uint32 u) {
    return __uint_as_float(u << 16) + __uint_as_float(u & 0xffff0000u);
}
static __device__ inline uint32 rot16(uint32 u) { return (u >> 16) | (u << 16); }
static __device__ inline u4v rot16v(u4v u) {
    u4v r; r[0] = rot16(u[0]); r[1] = rot16(u[1]); r[2] = rot16(u[2]); r[3] = rot16(u[3]);
    return r;
}

// ---- merged prep: [0,1536) wgint+wsum | [1536,2048) woutint | [2048,2336) rope ----
__global__ void prep_all(const float* __restrict__ w_qkv, const float* __restrict__ g,
                         uint32* __restrict__ wgint, float* __restrict__ wsum,
                         const float* __restrict__ w_out, uint32* __restrict__ woutint,
                         float* __restrict__ cosT, float* __restrict__ sinT) {
    __shared__ float red[256];
    int bid = blockIdx.x;
    int t = threadIdx.x;
    if (bid < QKV3) {
        int o = bid, c = t;
        float v = w_qkv[o * C_IN + c] * g[c];
        wgint[o * C_IN + c] = pk_rnd(v);
        red[c] = v;
        __syncthreads();
        for (int st = 128; st > 0; st >>= 1) {
            if (c < st) red[c] += red[c + st];
            __syncthreads();
        }
        if (c == 0) wsum[o] = red[0];
    } else if (bid < QKV3 + 512) {
        int idx = (bid - QKV3) * 256 + t;  // 131072 total
        woutint[idx] = pk_rnd(w_out[idx]);
    } else {
        int idx = (bid - QKV3 - 512) * 256 + t;  // 73728 total
        int s = idx >> 5, f = idx & 31;
        double inv = pow(10000.0, -(double)f / 32.0);
        double ang = (double)s * inv;
        cosT[idx] = (float)cos(ang);
        sinT[idx] = (float)sin(ang);
    }
}

// ------ transpose + pack x -> xTint[b][s][c] u32, and per-c-chunk LN partials ------
__global__ __launch_bounds__(256) void xt_pack(const float* __restrict__ x,
                                               uint32* __restrict__ xTint,
                                               float* __restrict__ psum,
                                               float* __restrict__ psq) {
    __shared__ float tile[64][65];
    __shared__ float sred[4][64];
    __shared__ float qred[4][64];
    int b = blockIdx.z;
    int c0 = blockIdx.y * 64;
    int s0 = blockIdx.x * 64;
    int t = threadIdx.x;
    int sl = t & 63, cg = t >> 6;
    float ps = 0.f, pq = 0.f;
#pragma unroll
    for (int i = 0; i < 16; ++i) {
        int c = cg * 16 + i;
        float v = x[((size_t)b * C_IN + c0 + c) * SS + s0 + sl];
        tile[c][sl] = v;
        ps += v;
        pq += v * v;
    }
    sred[cg][sl] = ps;
    qred[cg][sl] = pq;
    __syncthreads();
    int cl = t & 63, sg = t >> 6;
#pragma unroll
    for (int i = 0; i < 16; ++i) {
        int s = sg * 16 + i;
        xTint[((size_t)b * SS + s0 + s) * C_IN + c0 + cl] = pk_rnd(tile[cl][s]);
    }
    if (t < 64) {
        float S = (sred[0][t] + sred[1][t]) + (sred[2][t] + sred[3][t]);
        float Q = (qred[0][t] + qred[1][t]) + (qred[2][t] + qred[3][t]);
        size_t o = (size_t)blockIdx.y * (BATCH * SS) + (size_t)b * SS + s0 + t;
        psum[o] = S;
        psq[o] = Q;
    }
}

// ------------- QKV GEMM: interleaved hi/lo bf16 MFMA, LN folded epilogue -------------
// LN stats finalized inline from psum/psq partials (finalize_stats kernel removed).
// qkvint[b][o][s] = pack(rstd[s]*(sum_c wg[o][c]*x[c][s] - mean[s]*wsum[o]))
__global__ __launch_bounds__(256, 4) void qkv_mfma(
    const uint32* __restrict__ wgint, const uint32* __restrict__ xTint,
    const float* __restrict__ wsum, const float* __restrict__ psum,
    const float* __restrict__ psq, uint32* __restrict__ qkvint) {
    int b = blockIdx.z;
    int m0 = blockIdx.y * 128;  // o
    int n0 = blockIdx.x * 64;   // s
    int t = threadIdx.x;
    int wv = t >> 6, lane = t & 63, l15 = lane & 15, quad = lane >> 4;
    int wm = wv * 32;
    const uint32* Ab = wgint + (size_t)(m0 + wm) * C_IN;
    const uint32* Bb = xTint + ((size_t)b * SS + n0) * C_IN;
    f4v acc[2][4];
#pragma unroll
    for (int mt = 0; mt < 2; ++mt)
#pragma unroll
        for (int nt = 0; nt < 4; ++nt) acc[mt][nt] = (f4v){0.f, 0.f, 0.f, 0.f};
    u4v af[2][2], bf[2][4];
    auto ldA = [&](int ch, u4v* A) {
#pragma unroll
        for (int mt = 0; mt < 2; ++mt)
            A[mt] = *(const u4v*)(Ab + (size_t)(mt * 16 + l15) * C_IN + ch * 16 + quad * 4);
    };
    auto ldB = [&](int ch, u4v* B) {
#pragma unroll
        for (int nt = 0; nt < 4; ++nt)
            B[nt] = *(const u4v*)(Bb + (size_t)(nt * 16 + l15) * C_IN + ch * 16 + quad * 4);
    };
    ldA(0, af[0]);
    ldB(0, bf[0]);
#pragma unroll 2
    for (int ch = 0; ch < 16; ++ch) {
        int cur = ch & 1, nxt = cur ^ 1;
        if (ch + 1 < 16) { ldA(ch + 1, af[nxt]); ldB(ch + 1, bf[nxt]); }
        u4v br[4];
#pragma unroll
        for (int nt = 0; nt < 4; ++nt) br[nt] = rot16v(bf[cur][nt]);
#pragma unroll
        for (int mt = 0; mt < 2; ++mt) {
            s8v a = __builtin_bit_cast(s8v, af[cur][mt]);
#pragma unroll
            for (int nt = 0; nt < 4; ++nt) {
                acc[mt][nt] = mm(a, __builtin_bit_cast(s8v, bf[cur][nt]), acc[mt][nt]);
                acc[mt][nt] = mm(a, __builtin_bit_cast(s8v, br[nt]), acc[mt][nt]);
            }
        }
    }
    const int NP = BATCH * SS;
    float mnv[4], rsv[4];
#pragma unroll
    for (int nt = 0; nt < 4; ++nt) {
        int p = b * SS + n0 + nt * 16 + l15;
        float S = (psum[p] + psum[NP + p]) + (psum[2 * NP + p] + psum[3 * NP + p]);
        float Q = (psq[p] + psq[NP + p]) + (psq[2 * NP + p] + psq[3 * NP + p]);
        float mu = S * (1.0f / C_IN);
        mnv[nt] = mu;
        rsv[nt] = rsqrtf(Q * (1.0f / C_IN) - mu * mu + EPSV);
    }
#pragma unroll
    for (int mt = 0; mt < 2; ++mt)
#pragma unroll
        for (int r = 0; r < 4; ++r) {
            int m = m0 + wm + mt * 16 + quad * 4 + r;
            float ws = wsum[m];
            uint32* dst = qkvint + ((size_t)b * QKV3 + m) * SS + n0 + l15;
#pragma unroll
            for (int nt = 0; nt < 4; ++nt)
                dst[nt * 16] = pk_rnd(rsv[nt] * (acc[mt][nt][r] - mnv[nt] * ws));
        }
}

// ------- dwconv 3x3 + RoPE + hi/lo bf16 split.  Input qkvint packed u32.
// Q,K: [bh][s][d] (hi,lo separate); V: [bh][d][s] u32 = hi | lo<<16 -------
__global__ __launch_bounds__(256) void conv_rope(
    const uint32* __restrict__ qkvint, const float* __restrict__ dwq,
    const float* __restrict__ dwk, const float* __restrict__ dwv,
    const float* __restrict__ cosT, const float* __restrict__ sinT,
    unsigned short* __restrict__ qhi, unsigned short* __restrict__ qlo,
    unsigned short* __restrict__ khi, unsigned short* __restrict__ klo,
    uint32* __restrict__ vtint) {
    __shared__ float tile[64][65];
    int b = blockIdx.z;
    int part = blockIdx.y >> 3;
    int h = blockIdx.y & 7;
    int s0 = blockIdx.x * 64;
    int t = threadIdx.x;
    int sl = t & 63, dgrp = t >> 6;
    int s = s0 + sl;
    int y = s / 48, xx = s - y * 48;
    int bh = b * HEADS + h;
    const float* dw = (part == 0) ? dwq : (part == 1) ? dwk : dwv;
#pragma unroll
    for (int i = 0; i < 16; ++i) {
        int d = dgrp * 16 + i;
        int cch = part * HID + h * DH + d;
        const uint32* src = qkvint + ((size_t)b * QKV3 + cch) * SS;
        const float* wp = dw + (h * DH + d) * 9;
        float acc = 0.f;
#pragma unroll
        for (int dy = -1; dy <= 1; ++dy) {
            int yy = y + dy;
            if (yy < 0 || yy >= 48) continue;
#pragma unroll
            for (int dx = -1; dx <= 1; ++dx) {
                int xv = xx + dx;
                if (xv < 0 || xv >= 48) continue;
                acc += wp[(dy + 1) * 3 + (dx + 1)] * unpk(src[yy * 48 + xv]);
            }
        }
        if (part == 2) {
            size_t o = ((size_t)bh * DH + d) * SS + s;
            vtint[o] = pk_rnd(acc);
        } else {
            tile[d][sl] = acc;
        }
    }
    if (part == 2) return;
    __syncthreads();
    int d2 = t & 63, srow = t >> 6;
    unsigned short* hiA = (part == 0) ? qhi : khi;
    unsigned short* loA = (part == 0) ? qlo : klo;
#pragma unroll
    for (int i = 0; i < 16; ++i) {
        int sp = srow + 4 * i;
        float v0 = tile[d2][sp];
        float vp = tile[d2 ^ 32][sp];
        int f = d2 & 31;
        float cv = cosT[(s0 + sp) * 32 + f];
        float sv = sinT[(s0 + sp) * 32 + f];
        float rot = (d2 < 32) ? -vp : vp;
        float val = v0 * cv + rot * sv;
        if (part == 0) val *= SCALEV;
        size_t o = ((size_t)bh * SS + s0 + sp) * DH + d2;
        unsigned short hu = f2bf(val);
        hiA[o] = hu;
        loA[o] = f2bf(val - bf2f(hu));
    }
}

// -------- attention: key-split waves (16-key strip/wave, 64q x 16k), EXACT R7 loop
// (only spill-free config found: ~192 unified regs, 2 waves/SIMD, bounds (256,2);
// R6/R8/R9/R10 all spilled trying to exceed it).  No j-split: epilogue owns full l,
// writes normalized+packed OTint directly.  NEW: XCD-aware swizzle — consecutive
// dispatch ids round-robin XCDs, so map (n&7)->xcd-local bh group: each XCD's L2
// then holds only 4 bh's K/V (4.7 MB) instead of thrashing all 32 (R12 FETCH was
// 171 MB = 3x the 56.6 MB working set).  Correctness is mapping-independent. ----
__global__ __launch_bounds__(256, 2) void attn_mfma(
    const unsigned short* __restrict__ qhi, const unsigned short* __restrict__ qlo,
    const unsigned short* __restrict__ khi, const unsigned short* __restrict__ klo,
    const uint32* __restrict__ vtint, uint32* __restrict__ OTint) {
    __shared__ float lds[2][64][68];
    __shared__ float lsl[4][64];
    int n = blockIdx.y * 36 + blockIdx.x;   // 0..1151
    int xcd = n & 7, slot = n >> 3;         // slot 0..143
    int bh = (xcd << 2) | (slot / 36);      // 4 bh per XCD
    int i0 = (slot % 36) * 64;
    int t = threadIdx.x;
    int wv = t >> 6;
    int lane = t & 63;
    int l15 = lane & 15;
    int quad = lane >> 4;

    // Q B-frags: B[n=query(l15)][k=d(quad*8+j)] for 4 query groups, hi/lo
    s8v qf[4][4];
#pragma unroll
    for (int ig = 0; ig < 4; ++ig) {
        size_t qb = ((size_t)bh * SS + i0 + ig * 16 + l15) * DH + quad * 8;
        qf[ig][0] = *(const s8v*)(qhi + qb);
        qf[ig][1] = *(const s8v*)(qhi + qb + 32);
        qf[ig][2] = *(const s8v*)(qlo + qb);
        qf[ig][3] = *(const s8v*)(qlo + qb + 32);
    }
    f4v oacc[4][4];
#pragma unroll
    for (int dt = 0; dt < 4; ++dt)
#pragma unroll
        for (int ig = 0; ig < 4; ++ig) oacc[dt][ig] = (f4v){0.f, 0.f, 0.f, 0.f};
    float lsum[4] = {0.f, 0.f, 0.f, 0.f};

    const size_t kbh = (size_t)bh * SS * DH;
    const uint32* vbase = vtint + (size_t)bh * DH * SS;
    const int jbase = wv * 16;  // wave's strip base; + s*64 per step

    s8v kc[2][4], vc[2][4];
    auto ldK = [&](int s, s8v* K) {
        size_t row = kbh + (size_t)(jbase + s * 64 + l15) * DH + quad * 8;
        K[0] = *(const s8v*)(khi + row);
        K[1] = *(const s8v*)(khi + row + 32);
        K[2] = *(const s8v*)(klo + row);
        K[3] = *(const s8v*)(klo + row + 32);
    };
    auto ldV = [&](int s, s8v* V) {
        size_t col = (size_t)(jbase + s * 64 + quad * 4);
#pragma unroll
        for (int dt = 0; dt < 4; ++dt)
            V[dt] = __builtin_bit_cast(
                s8v, *(const u4v*)(vbase + (size_t)(dt * 16 + l15) * SS + col));
    };
    ldK(0, kc[0]);
    ldV(0, vc[0]);
#pragma unroll 2
    for (int s = 0; s < 36; ++s) {
        int cur = s & 1, nxt = cur ^ 1;
        if (s + 1 < 36) { ldK(s + 1, kc[nxt]); ldV(s + 1, vc[nxt]); }
        // ---- S^T strip = K_strip . Q^T : C row = key quad*4+r, col = query l15 ----
        f4v sv[4];
#pragma unroll
        for (int ig = 0; ig < 4; ++ig) {
            f4v sx = {0.f, 0.f, 0.f, 0.f};
            sx = mm(kc[cur][0], qf[ig][0], sx);
            sx = mm(kc[cur][1], qf[ig][1], sx);
            sx = mm(kc[cur][0], qf[ig][2], sx);
            sx = mm(kc[cur][1], qf[ig][3], sx);
            sx = mm(kc[cur][2], qf[ig][0], sx);
            sx = mm(kc[cur][3], qf[ig][1], sx);
            sv[ig] = sx;
        }
        // ---- p = exp(s); pack B1 = {ph|pl}, B2 = {pl|ph} per key (in-lane!) ----
        s8v B1[4], B2[4];
#pragma unroll
        for (int ig = 0; ig < 4; ++ig) {
            float p0 = __expf(sv[ig][0]), p1 = __expf(sv[ig][1]);
            float p2 = __expf(sv[ig][2]), p3 = __expf(sv[ig][3]);
            lsum[ig] += (p0 + p1) + (p2 + p3);
            uint32 u0 = pk_trunc(p0), u1 = pk_trunc(p1);
            uint32 u2 = pk_trunc(p2), u3 = pk_trunc(p3);
            B1[ig] = pk4(u0, u1, u2, u3);
            B2[ig] = pk4(rot16(u0), rot16(u1), rot16(u2), rot16(u3));
        }
        // ---- O^T += V^T_strip . P^T: A = interleaved {vh|vl} u32/key (1 load) ----
        // mm(A,B1) = vh.ph + vl.pl ; mm(A,B2) = vh.pl + vl.ph  => exact product
#pragma unroll
        for (int dt = 0; dt < 4; ++dt)
#pragma unroll
            for (int ig = 0; ig < 4; ++ig) {
                oacc[dt][ig] = mm(vc[cur][dt], B1[ig], oacc[dt][ig]);
                oacc[dt][ig] = mm(vc[cur][dt], B2[ig], oacc[dt][ig]);
            }
    }
    // ---- l: reduce over quads (keys) in-wave; cross-wave via LDS ----
#pragma unroll
    for (int ig = 0; ig < 4; ++ig) {
        float v = lsum[ig];
        v += __shfl_xor(v, 16);
        v += __shfl_xor(v, 32);
        if (quad == 0) lsl[wv][ig * 16 + l15] = v;
    }
    // ---- phased epilogue: waves 0,1 write slots; waves 2,3 accumulate in-place ----
    if (wv < 2) {
#pragma unroll
        for (int dt = 0; dt < 4; ++dt)
#pragma unroll
            for (int ig = 0; ig < 4; ++ig)
#pragma unroll
                for (int r = 0; r < 4; ++r)
                    lds[wv][dt * 16 + quad * 4 + r][ig * 16 + l15] = oacc[dt][ig][r];
    }
    __syncthreads();
    if (wv >= 2) {
#pragma unroll
        for (int dt = 0; dt < 4; ++dt)
#pragma unroll
            for (int ig = 0; ig < 4; ++ig)
#pragma unroll
                for (int r = 0; r < 4; ++r)
                    lds[wv - 2][dt * 16 + quad * 4 + r][ig * 16 + l15] += oacc[dt][ig][r];
    }
    __syncthreads();
    // ---- normalize + pack + write OTint[b][s][h*64+d] (full l known: no combine) ----
    int q = t >> 2, dg = t & 3;
    float linv = 1.f / ((lsl[0][q] + lsl[1][q]) + (lsl[2][q] + lsl[3][q]));
    int b = bh >> 3, h = bh & 7;
    uint32* dst = OTint + ((size_t)b * SS + i0 + q) * HID + h * DH + dg * 16;
    u4v ov[4];
#pragma unroll
    for (int j4 = 0; j4 < 4; ++j4)
#pragma unroll
        for (int i = 0; i < 4; ++i) {
            int d = dg * 16 + j4 * 4 + i;
            ov[j4][i] = pk_rnd((lds[0][d][q] + lds[1][d][q]) * linv);
        }
#pragma unroll
    for (int j4 = 0; j4 < 4; ++j4) *(u4v*)(dst + j4 * 4) = ov[j4];
}

// ------------- output projection: interleaved hi/lo bf16 MFMA + bias -------------
__global__ __launch_bounds__(256, 4) void outproj_mfma(
    const uint32* __restrict__ OTint, const uint32* __restrict__ woutint,
    const float* __restrict__ b_out, float* __restrict__ out) {
    int b = blockIdx.z;
    int m0 = blockIdx.y * 32;   // o
    int n0 = blockIdx.x * 128;  // s
    int t = threadIdx.x;
    int wv = t >> 6, lane = t & 63, l15 = lane & 15, quad = lane >> 4;
    int wn = wv * 32;
    const uint32* Ab = woutint + (size_t)m0 * HID;
    const uint32* Bb = OTint + ((size_t)b * SS + n0 + wn) * HID;
    f4v acc[2][2];
#pragma unroll
    for (int mt = 0; mt < 2; ++mt)
#pragma unroll
        for (int nt = 0; nt < 2; ++nt) acc[mt][nt] = (f4v){0.f, 0.f, 0.f, 0.f};
    u4v af[2][2], bf[2][2];
    auto ldA = [&](int ch, u4v* A) {
#pragma unroll
        for (int mt = 0; mt < 2; ++mt)
            A[mt] = *(const u4v*)(Ab + (size_t)(mt * 16 + l15) * HID + ch * 16 + quad * 4);
    };
    auto ldB = [&](int ch, u4v* B) {
#pragma unroll
        for (int nt = 0; nt < 2; ++nt)
            B[nt] = *(const u4v*)(Bb + (size_t)(nt * 16 + l15) * HID + ch * 16 + quad * 4);
    };
    ldA(0, af[0]);
    ldB(0, bf[0]);
#pragma unroll 2
    for (int ch = 0; ch < 32; ++ch) {
        int cur = ch & 1, nxt = cur ^ 1;
        if (ch + 1 < 32) { ldA(ch + 1, af[nxt]); ldB(ch + 1, bf[nxt]); }
        u4v br[2];
#pragma unroll
        for (int nt = 0; nt < 2; ++nt) br[nt] = rot16v(bf[cur][nt]);
#pragma unroll
        for (int mt = 0; mt < 2; ++mt) {
            s8v a = __builtin_bit_cast(s8v, af[cur][mt]);
#pragma unroll
            for (int nt = 0; nt < 2; ++nt) {
                acc[mt][nt] = mm(a, __builtin_bit_cast(s8v, bf[cur][nt]), acc[mt][nt]);
                acc[mt][nt] = mm(a, __builtin_bit_cast(s8v, br[nt]), acc[mt][nt]);
            }
        }
    }
#pragma unroll
    for (int mt = 0; mt < 2; ++mt)
#pragma unroll
        for (int r = 0; r < 4; ++r) {
            int o = m0 + mt * 16 + quad * 4 + r;
            float bo = b_out[o];
            float* dst = out + ((size_t)b * C_IN + o) * SS + n0 + wn + l15;
#pragma unroll
            for (int nt = 0; nt < 2; ++nt) dst[nt * 16] = acc[mt][nt][r] + bo;
        }
}

extern "C" void kernel_launch(void* const* d_in, const int* in_sizes, int n_in,
                              void* d_out, int out_size, void* d_ws, size_t ws_size,
                              hipStream_t stream) {
    (void)in_sizes; (void)n_in; (void)out_size; (void)ws_size;
    const float* x     = (const float*)d_in[0];
    const float* g     = (const float*)d_in[1];
    const float* w_qkv = (const float*)d_in[2];
    const float* dwq   = (const float*)d_in[3];
    const float* dwk   = (const float*)d_in[4];
    const float* dwv   = (const float*)d_in[5];
    const float* w_out = (const float*)d_in[6];
    const float* b_out = (const float*)d_in[7];
    float* out = (float*)d_out;

    char* ws = (char*)d_ws;
    size_t off = 0;
    auto alloc = [&](size_t nbytes) -> void* {
        char* p = ws + off;
        off = (off + nbytes + 255) & ~(size_t)255;
        return (void*)p;
    };
    const size_t NSD = (size_t)BATCH * HEADS * SS * DH;  // 4.7M elements
    uint32* wgint   = (uint32*)alloc((size_t)QKV3 * C_IN * 4);
    uint32* woutint = (uint32*)alloc((size_t)C_IN * HID * 4);
    float* wsum = (float*)alloc((size_t)QKV3 * 4);
    float* psum = (float*)alloc((size_t)4 * BATCH * SS * 4);
    float* psq  = (float*)alloc((size_t)4 * BATCH * SS * 4);
    float* cosT = (float*)alloc((size_t)SS * 32 * 4);
    float* sinT = (float*)alloc((size_t)SS * 32 * 4);
    // scratchA: qkvint = BATCH*QKV3*SS u32 = 3*NSD u32 = 56.6 MB.
    // OTint (NSD u32) aliases its start — qkvint dead after conv_rope.
    char* scratchA = (char*)alloc((size_t)3 * NSD * 4);
    unsigned short* qhi  = (unsigned short*)alloc(NSD * 2);
    unsigned short* qlo  = (unsigned short*)alloc(NSD * 2);
    unsigned short* khi  = (unsigned short*)alloc(NSD * 2);
    unsigned short* klo  = (unsigned short*)alloc(NSD * 2);
    uint32* vtint = (uint32*)alloc(NSD * 4);
    // aliases (time-disjoint):
    uint32* xTint  = (uint32*)qhi;      // dead before conv_rope writes qhi
    uint32* qkvint = (uint32*)scratchA; // dead after conv_rope
    uint32* OTint  = (uint32*)scratchA;

    prep_all<<<QKV3 + 512 + 288, 256, 0, stream>>>(w_qkv, g, wgint, wsum,
                                                   w_out, woutint, cosT, sinT);
    xt_pack<<<dim3(36, 4, BATCH), 256, 0, stream>>>(x, xTint, psum, psq);
    qkv_mfma<<<dim3(36, 12, BATCH), 256, 0, stream>>>(wgint, xTint, wsum, psum, psq,
                                                      qkvint);
    conv_rope<<<dim3(36, 24, BATCH), 256, 0, stream>>>(qkvint, dwq, dwk, dwv, cosT, sinT,
                                                       qhi, qlo, khi, klo, vtint);
    attn_mfma<<<dim3(36, 32), 256, 0, stream>>>(qhi, qlo, khi, klo, vtint, OTint);
    outproj_mfma<<<dim3(18, 8, BATCH), 256, 0, stream>>>(OTint, woutint, b_out, out);
}